// Round 9
// baseline (863.669 us; speedup 1.0000x reference)
//
#include <hip/hip_runtime.h>
#include <math.h>

typedef _Float16 f16x8 __attribute__((ext_vector_type(8)));
typedef float f32x4 __attribute__((ext_vector_type(4)));

__device__ __forceinline__ float us2f(unsigned short u) {
  _Float16 h;
  __builtin_memcpy(&h, &u, 2);
  return (float)h;
}
__device__ __forceinline__ unsigned short f2us(float f) {
  _Float16 h = (_Float16)f;
  unsigned short u;
  __builtin_memcpy(&u, &h, 2);
  return u;
}
__device__ __forceinline__ int2 nt_load_i2(const int2* p) {
  long long raw = __builtin_nontemporal_load((const long long*)p);
  int2 v;
  __builtin_memcpy(&v, &raw, 8);
  return v;
}
__device__ __forceinline__ ushort4 nt_load_us4(const ushort4* p) {
  unsigned long long raw = __builtin_nontemporal_load((const unsigned long long*)p);
  ushort4 v;
  __builtin_memcpy(&v, &raw, 8);
  return v;
}

// ---------------- CSR build: histogram (XCD-partitioned dst ranges, nt streams) ----------------
__global__ __launch_bounds__(256) void hist_k(const int* __restrict__ dst, int* __restrict__ deg,
                                              int E, int N) {
  int xcd = blockIdx.x & 7;
  int bid = blockIdx.x >> 3;
  int nb = gridDim.x >> 3;
  int R = (N + 7) >> 3;
  int lo = xcd * R;
  int hi = min(N, lo + R);
  for (int e = bid * blockDim.x + threadIdx.x; e < E; e += nb * blockDim.x) {
    int d = __builtin_nontemporal_load(dst + e);
    if (d >= lo && d < hi) atomicAdd(&deg[d], 1);
  }
}

// ---------------- CSR build: 3-kernel exclusive scan ----------------
__global__ __launch_bounds__(1024) void scan1_k(const int* __restrict__ deg, int* __restrict__ rp,
                                                int* __restrict__ bsum, int n) {
  __shared__ int buf[2][1024];
  int tid = threadIdx.x;
  int i = blockIdx.x * 1024 + tid;
  int v = (i < n) ? deg[i] : 0;
  int pp = 0;
  buf[0][tid] = v;
  __syncthreads();
  for (int off = 1; off < 1024; off <<= 1) {
    int t = buf[pp][tid];
    if (tid >= off) t += buf[pp][tid - off];
    buf[pp ^ 1][tid] = t;
    pp ^= 1;
    __syncthreads();
  }
  int inc = buf[pp][tid];
  if (i < n) rp[i] = inc - v;
  if (tid == 1023) bsum[blockIdx.x] = inc;
}

__global__ __launch_bounds__(256) void scan2_k(int* __restrict__ bsum, int nb) {
  __shared__ int buf[2][256];
  int tid = threadIdx.x;
  int v = (tid < nb) ? bsum[tid] : 0;
  int pp = 0;
  buf[0][tid] = v;
  __syncthreads();
  for (int off = 1; off < 256; off <<= 1) {
    int t = buf[pp][tid];
    if (tid >= off) t += buf[pp][tid - off];
    buf[pp ^ 1][tid] = t;
    pp ^= 1;
    __syncthreads();
  }
  if (tid < nb) bsum[tid] = buf[pp][tid] - v;
}

__global__ __launch_bounds__(1024) void scan3_k(int* __restrict__ rp, int* __restrict__ cur,
                                                const int* __restrict__ bsum, int n, int E) {
  int i = blockIdx.x * 1024 + threadIdx.x;
  if (i < n) {
    int v = rp[i] + bsum[blockIdx.x];
    rp[i] = v;
    cur[i] = v;
  }
  if (i == 0) rp[n] = E;
}

// ---------------- CSR build: counting-sort scatter (XCD-partitioned, nt streams) ----------------
__global__ __launch_bounds__(256) void scatter_k(const int* __restrict__ src, const int* __restrict__ dst,
                                                 const float* __restrict__ w, int* __restrict__ cur,
                                                 int2* __restrict__ edge, int* __restrict__ eidx,
                                                 int E, int N) {
  int xcd = blockIdx.x & 7;
  int bid = blockIdx.x >> 3;
  int nb = gridDim.x >> 3;
  int R = (N + 7) >> 3;
  int lo = xcd * R;
  int hi = min(N, lo + R);
  for (int e = bid * blockDim.x + threadIdx.x; e < E; e += nb * blockDim.x) {
    int d = __builtin_nontemporal_load(dst + e);
    int s = __builtin_nontemporal_load(src + e);
    float ww = __builtin_nontemporal_load(w + e);
    if (d >= lo && d < hi) {
      int pos = atomicAdd(&cur[d], 1);
      edge[pos] = make_int2(s, __float_as_int(ww));
      eidx[pos] = e;
    }
  }
}

// ---------------- canonicalize: selection-sort each node's segment by original edge index ----------------
__global__ __launch_bounds__(256) void sortpack_k(int* __restrict__ eidx, int2* __restrict__ edge,
                                                  const int* __restrict__ rp, int n) {
  int node = blockIdx.x * 256 + threadIdx.x;
  if (node >= n) return;
  int beg = rp[node], end = rp[node + 1];
  for (int i = beg; i < end - 1; ++i) {
    int mi = i, mv = eidx[i];
    for (int j = i + 1; j < end; ++j) {
      int v = eidx[j];
      if (v < mv) { mv = v; mi = j; }
    }
    if (mi != i) {
      eidx[mi] = eidx[i];
      eidx[i] = mv;
      int2 t = edge[i];
      edge[i] = edge[mi];
      edge[mi] = t;
    }
  }
}

// ---------------- x0 = relu(x @ W_in + b_in)  [MFMA hi/lo split, fp16 out] ----------------
__global__ __launch_bounds__(256) void ingemm_k(const float* __restrict__ x, const float* __restrict__ Win,
                                                const float* __restrict__ bin, unsigned short* __restrict__ x0,
                                                int n) {
  int lane = threadIdx.x & 63;
  int wave = threadIdx.x >> 6;
  int col = lane & 15, grp = lane >> 4;
  f16x8 Bh[4][4], Bl[4][4];
#pragma unroll
  for (int c = 0; c < 4; ++c)
#pragma unroll
    for (int t = 0; t < 4; ++t) {
      f16x8 bh, bl;
#pragma unroll
      for (int j = 0; j < 8; ++j) {
        float wv = Win[(c * 32 + grp * 8 + j) * 64 + t * 16 + col];
        _Float16 hi = (_Float16)wv;
        bh[j] = hi;
        bl[j] = (_Float16)(wv - (float)hi);
      }
      Bh[c][t] = bh;
      Bl[c][t] = bl;
    }
  float bb[4];
#pragma unroll
  for (int t = 0; t < 4; ++t) bb[t] = bin[t * 16 + col];

  int node_base = (blockIdx.x * 4 + wave) * 16;
  if (node_base >= n) return;
  int arow = node_base + col;
  if (arow > n - 1) arow = n - 1;
  const float* xr = x + (size_t)arow * 128 + grp * 8;

  f32x4 acc[4];
  f32x4 z = {0.f, 0.f, 0.f, 0.f};
#pragma unroll
  for (int t = 0; t < 4; ++t) acc[t] = z;
#pragma unroll
  for (int c = 0; c < 4; ++c) {
    f32x4 lo = *(const f32x4*)(xr + c * 32);
    f32x4 hi = *(const f32x4*)(xr + c * 32 + 4);
    f16x8 ah, al;
#pragma unroll
    for (int j = 0; j < 4; ++j) {
      _Float16 h0 = (_Float16)lo[j];
      ah[j] = h0;
      al[j] = (_Float16)(lo[j] - (float)h0);
      _Float16 h1 = (_Float16)hi[j];
      ah[4 + j] = h1;
      al[4 + j] = (_Float16)(hi[j] - (float)h1);
    }
#pragma unroll
    for (int t = 0; t < 4; ++t) {
      acc[t] = __builtin_amdgcn_mfma_f32_16x16x32_f16(ah, Bh[c][t], acc[t], 0, 0, 0);
      acc[t] = __builtin_amdgcn_mfma_f32_16x16x32_f16(al, Bh[c][t], acc[t], 0, 0, 0);
      acc[t] = __builtin_amdgcn_mfma_f32_16x16x32_f16(ah, Bl[c][t], acc[t], 0, 0, 0);
    }
  }
#pragma unroll
  for (int t = 0; t < 4; ++t)
#pragma unroll
    for (int r = 0; r < 4; ++r) {
      int node = node_base + grp * 4 + r;
      if (node < n) {
        float o = acc[t][r] + bb[t];
        x0[(size_t)node * 64 + t * 16 + col] = f2us(fmaxf(o, 0.f));
      }
    }
}

// ---------------- fused layer: SpMM gather -> f32 LDS -> hi/lo MFMA GEMM + f32 identity ----------------
__global__ __launch_bounds__(256) void layer_fused_k(const ushort4* __restrict__ hin4,
                                                     const ushort4* __restrict__ x04,
                                                     const int* __restrict__ rp, const int2* __restrict__ edge,
                                                     const float* __restrict__ W,
                                                     unsigned short* __restrict__ hout,
                                                     float beta, int n) {
  __shared__ float hh_lds[64][72];
  int lane = threadIdx.x & 63;
  int wave = threadIdx.x >> 6;
  int q = lane >> 4;   // node slot
  int sl = lane & 15;  // feature quad
  int blockStart = blockIdx.x * 64;

  // ---- gather phase (fp16 h rows, f32 accumulate, f32 hh to LDS) ----
#pragma unroll
  for (int r = 0; r < 4; ++r) {
    int nib = wave * 16 + r * 4 + q;
    int node = blockStart + nib;
    float a0 = 0.f, a1 = 0.f, a2 = 0.f, a3 = 0.f;
    ushort4 xv = make_ushort4(0, 0, 0, 0);
    if (node < n) {
      int beg = __builtin_nontemporal_load(rp + node);
      int end = __builtin_nontemporal_load(rp + node + 1);
      xv = nt_load_us4(x04 + (size_t)node * 16 + sl);
      for (int e = beg; e < end; e += 8) {
        int2 d[8];
#pragma unroll
        for (int j = 0; j < 8; ++j) d[j] = (e + j < end) ? nt_load_i2(edge + e + j) : make_int2(0, 0);
        ushort4 v[8];
#pragma unroll
        for (int j = 0; j < 8; ++j) v[j] = hin4[(size_t)d[j].x * 16 + sl];
#pragma unroll
        for (int j = 0; j < 8; ++j) {
          float w = __int_as_float(d[j].y);
          a0 = fmaf(us2f(v[j].x), w, a0);
          a1 = fmaf(us2f(v[j].y), w, a1);
          a2 = fmaf(us2f(v[j].z), w, a2);
          a3 = fmaf(us2f(v[j].w), w, a3);
        }
      }
    }
    float4 o;
    o.x = fmaf(0.9f, a0, 0.1f * us2f(xv.x));
    o.y = fmaf(0.9f, a1, 0.1f * us2f(xv.y));
    o.z = fmaf(0.9f, a2, 0.1f * us2f(xv.z));
    o.w = fmaf(0.9f, a3, 0.1f * us2f(xv.w));
    *(float4*)&hh_lds[nib][sl * 4] = o;
  }
  __syncthreads();

  // ---- GEMM phase: A = cvt(hh), B = W split hi/lo ----
  int col = lane & 15, grp = lane >> 4;
  f16x8 Bh[2][4], Bl[2][4];
#pragma unroll
  for (int c = 0; c < 2; ++c)
#pragma unroll
    for (int t = 0; t < 4; ++t) {
      f16x8 bh, bl;
#pragma unroll
      for (int j = 0; j < 8; ++j) {
        float wv = W[(c * 32 + grp * 8 + j) * 64 + t * 16 + col];
        _Float16 hi = (_Float16)wv;
        bh[j] = hi;
        bl[j] = (_Float16)(wv - (float)hi);
      }
      Bh[c][t] = bh;
      Bl[c][t] = bl;
    }
  f16x8 A0, A1;
#pragma unroll
  for (int j = 0; j < 8; ++j) {
    A0[j] = (_Float16)hh_lds[wave * 16 + col][j + grp * 8];
    A1[j] = (_Float16)hh_lds[wave * 16 + col][32 + j + grp * 8];
  }

  f32x4 acc[4];
  f32x4 z = {0.f, 0.f, 0.f, 0.f};
#pragma unroll
  for (int t = 0; t < 4; ++t) acc[t] = z;
#pragma unroll
  for (int t = 0; t < 4; ++t) {
    acc[t] = __builtin_amdgcn_mfma_f32_16x16x32_f16(A0, Bh[0][t], acc[t], 0, 0, 0);
    acc[t] = __builtin_amdgcn_mfma_f32_16x16x32_f16(A1, Bh[1][t], acc[t], 0, 0, 0);
    acc[t] = __builtin_amdgcn_mfma_f32_16x16x32_f16(A0, Bl[0][t], acc[t], 0, 0, 0);
    acc[t] = __builtin_amdgcn_mfma_f32_16x16x32_f16(A1, Bl[1][t], acc[t], 0, 0, 0);
  }
  float ob = 1.f - beta;
  int node_base = blockStart + wave * 16;
#pragma unroll
  for (int t = 0; t < 4; ++t)
#pragma unroll
    for (int r = 0; r < 4; ++r) {
      int node = node_base + grp * 4 + r;
      if (node < n) {
        float hv = hh_lds[wave * 16 + grp * 4 + r][t * 16 + col];  // f32 identity term
        float o = ob * hv + beta * acc[t][r];
        __builtin_nontemporal_store(f2us(fmaxf(o, 0.f)), hout + (size_t)node * 64 + t * 16 + col);
      }
    }
}

// ---------------- out = log_softmax(h @ W_out + b_out)  [MFMA hi/lo split, fp16 in, f32 out] ----------------
__global__ __launch_bounds__(256) void out_k(const unsigned short* __restrict__ h,
                                             const float* __restrict__ Wout, const float* __restrict__ bout,
                                             float* __restrict__ out, int n) {
  int lane = threadIdx.x & 63;
  int wave = threadIdx.x >> 6;
  int col = lane & 15, grp = lane >> 4;
  f16x8 Bh[2][3], Bl[2][3];
#pragma unroll
  for (int c = 0; c < 2; ++c)
#pragma unroll
    for (int t = 0; t < 3; ++t) {
      int cls = t * 16 + col;
      f16x8 bh, bl;
#pragma unroll
      for (int j = 0; j < 8; ++j) {
        float wv = (cls < 40) ? Wout[(c * 32 + grp * 8 + j) * 40 + cls] : 0.f;
        _Float16 hi = (_Float16)wv;
        bh[j] = hi;
        bl[j] = (_Float16)(wv - (float)hi);
      }
      Bh[c][t] = bh;
      Bl[c][t] = bl;
    }
  float bb[3];
#pragma unroll
  for (int t = 0; t < 3; ++t) {
    int cls = t * 16 + col;
    bb[t] = (cls < 40) ? bout[cls] : 0.f;
  }
  int node_base = (blockIdx.x * 4 + wave) * 16;
  if (node_base >= n) return;
  int arow = node_base + col;
  if (arow > n - 1) arow = n - 1;
  const unsigned short* rowp = h + (size_t)arow * 64 + grp * 8;
  f16x8 A0 = *(const f16x8*)(rowp);
  f16x8 A1 = *(const f16x8*)(rowp + 32);

  f32x4 acc[3];
  f32x4 z = {0.f, 0.f, 0.f, 0.f};
#pragma unroll
  for (int t = 0; t < 3; ++t) acc[t] = z;
#pragma unroll
  for (int t = 0; t < 3; ++t) {
    acc[t] = __builtin_amdgcn_mfma_f32_16x16x32_f16(A0, Bh[0][t], acc[t], 0, 0, 0);
    acc[t] = __builtin_amdgcn_mfma_f32_16x16x32_f16(A1, Bh[1][t], acc[t], 0, 0, 0);
    acc[t] = __builtin_amdgcn_mfma_f32_16x16x32_f16(A0, Bl[0][t], acc[t], 0, 0, 0);
    acc[t] = __builtin_amdgcn_mfma_f32_16x16x32_f16(A1, Bl[1][t], acc[t], 0, 0, 0);
  }
#pragma unroll
  for (int r = 0; r < 4; ++r) {
    int node = node_base + grp * 4 + r;
    float v0 = acc[0][r] + bb[0];
    float v1 = acc[1][r] + bb[1];
    float v2 = (32 + col < 40) ? (acc[2][r] + bb[2]) : -INFINITY;
    float m = fmaxf(fmaxf(v0, v1), v2);
#pragma unroll
    for (int mask = 1; mask <= 8; mask <<= 1) m = fmaxf(m, __shfl_xor(m, mask, 64));
    float p = expf(v0 - m) + expf(v1 - m) + ((32 + col < 40) ? expf(v2 - m) : 0.f);
#pragma unroll
    for (int mask = 1; mask <= 8; mask <<= 1) p += __shfl_xor(p, mask, 64);
    float ml = m + logf(p);
    if (node < n) {
      out[(size_t)node * 40 + col] = v0 - ml;
      out[(size_t)node * 40 + 16 + col] = v1 - ml;
      if (32 + col < 40) out[(size_t)node * 40 + 32 + col] = v2 - ml;
    }
  }
}

extern "C" void kernel_launch(void* const* d_in, const int* in_sizes, int n_in,
                              void* d_out, int out_size, void* d_ws, size_t ws_size,
                              hipStream_t stream) {
  const float* x = (const float*)d_in[0];
  const int* esrc = (const int*)d_in[1];
  const int* edst = (const int*)d_in[2];
  const float* ew = (const float*)d_in[3];
  const float* Win = (const float*)d_in[4];
  const float* bin = (const float*)d_in[5];
  const float* convW = (const float*)d_in[6];
  const float* Wout = (const float*)d_in[7];
  const float* bout = (const float*)d_in[8];
  float* out = (float*)d_out;

  const int N = in_sizes[0] / 128;
  const int E = in_sizes[1];
  const int NC = in_sizes[6] / (64 * 64);

  char* ws = (char*)d_ws;
  size_t off = 0;
  auto alloc = [&](size_t b) {
    void* p = ws + off;
    off += (b + 255) & ~(size_t)255;
    return p;
  };
  unsigned short* x0 = (unsigned short*)alloc((size_t)N * 64 * 2);
  unsigned short* ha = (unsigned short*)alloc((size_t)N * 64 * 2);
  unsigned short* hb = (unsigned short*)alloc((size_t)N * 64 * 2);
  int* deg = (int*)alloc((size_t)N * 4);
  int* rp = (int*)alloc((size_t)(N + 1) * 4);
  int* cur = (int*)alloc((size_t)N * 4);
  int* bsum = (int*)alloc(1024);
  int2* edge = (int2*)alloc((size_t)E * 8);
  int* eidx = (int*)alloc((size_t)E * 4);

  hipMemsetAsync(deg, 0, (size_t)N * 4, stream);
  hist_k<<<2048, 256, 0, stream>>>(edst, deg, E, N);
  int nb = (N + 1023) / 1024;
  scan1_k<<<nb, 1024, 0, stream>>>(deg, rp, bsum, N);
  scan2_k<<<1, 256, 0, stream>>>(bsum, nb);
  scan3_k<<<nb, 1024, 0, stream>>>(rp, cur, bsum, N, E);
  scatter_k<<<2048, 256, 0, stream>>>(esrc, edst, ew, cur, edge, eidx, E, N);
  sortpack_k<<<(N + 255) / 256, 256, 0, stream>>>(eidx, edge, rp, N);

  int gblocks = (N + 63) / 64;
  ingemm_k<<<gblocks, 256, 0, stream>>>(x, Win, bin, x0, N);

  const unsigned short* hin = x0;
  unsigned short* bufs[2] = {ha, hb};
  for (int l = 0; l < NC; ++l) {
    float beta = logf(0.5f / (float)(l + 1) + 1.0f);
    unsigned short* ho = bufs[l & 1];
    layer_fused_k<<<gblocks, 256, 0, stream>>>((const ushort4*)hin, (const ushort4*)x0, rp, edge,
                                               convW + (size_t)l * 64 * 64, ho, beta, N);
    hin = ho;
  }
  out_k<<<gblocks, 256, 0, stream>>>(hin, Wout, bout, out, N);
}

// Round 12
// 739.158 us; speedup vs baseline: 1.1684x; 1.1684x over previous
//
#include <hip/hip_runtime.h>
#include <math.h>

typedef _Float16 f16x8 __attribute__((ext_vector_type(8)));
typedef float f32x4 __attribute__((ext_vector_type(4)));

// ---------------- CSR build: histogram (XCD-partitioned dst ranges, nt streams) ----------------
__global__ __launch_bounds__(256) void hist_k(const int* __restrict__ dst, int* __restrict__ deg,
                                              int E, int N) {
  int xcd = blockIdx.x & 7;
  int bid = blockIdx.x >> 3;
  int nb = gridDim.x >> 3;
  int R = (N + 7) >> 3;
  int lo = xcd * R;
  int hi = min(N, lo + R);
  for (int e = bid * blockDim.x + threadIdx.x; e < E; e += nb * blockDim.x) {
    int d = __builtin_nontemporal_load(dst + e);
    if (d >= lo && d < hi) atomicAdd(&deg[d], 1);
  }
}

// ---------------- CSR build: 3-kernel exclusive scan ----------------
__global__ __launch_bounds__(1024) void scan1_k(const int* __restrict__ deg, int* __restrict__ rp,
                                                int* __restrict__ bsum, int n) {
  __shared__ int buf[2][1024];
  int tid = threadIdx.x;
  int i = blockIdx.x * 1024 + tid;
  int v = (i < n) ? deg[i] : 0;
  int pp = 0;
  buf[0][tid] = v;
  __syncthreads();
  for (int off = 1; off < 1024; off <<= 1) {
    int t = buf[pp][tid];
    if (tid >= off) t += buf[pp][tid - off];
    buf[pp ^ 1][tid] = t;
    pp ^= 1;
    __syncthreads();
  }
  int inc = buf[pp][tid];
  if (i < n) rp[i] = inc - v;
  if (tid == 1023) bsum[blockIdx.x] = inc;
}

__global__ __launch_bounds__(256) void scan2_k(int* __restrict__ bsum, int nb) {
  __shared__ int buf[2][256];
  int tid = threadIdx.x;
  int v = (tid < nb) ? bsum[tid] : 0;
  int pp = 0;
  buf[0][tid] = v;
  __syncthreads();
  for (int off = 1; off < 256; off <<= 1) {
    int t = buf[pp][tid];
    if (tid >= off) t += buf[pp][tid - off];
    buf[pp ^ 1][tid] = t;
    pp ^= 1;
    __syncthreads();
  }
  if (tid < nb) bsum[tid] = buf[pp][tid] - v;
}

__global__ __launch_bounds__(1024) void scan3_k(int* __restrict__ rp, int* __restrict__ cur,
                                                const int* __restrict__ bsum, int n, int E) {
  int i = blockIdx.x * 1024 + threadIdx.x;
  if (i < n) {
    int v = rp[i] + bsum[blockIdx.x];
    rp[i] = v;
    cur[i] = v;
  }
  if (i == 0) rp[n] = E;
}

// ---------------- CSR build: counting-sort scatter (XCD-partitioned, nt streams) ----------------
__global__ __launch_bounds__(256) void scatter_k(const int* __restrict__ src, const int* __restrict__ dst,
                                                 const float* __restrict__ w, int* __restrict__ cur,
                                                 int2* __restrict__ edge, int* __restrict__ eidx,
                                                 int E, int N) {
  int xcd = blockIdx.x & 7;
  int bid = blockIdx.x >> 3;
  int nb = gridDim.x >> 3;
  int R = (N + 7) >> 3;
  int lo = xcd * R;
  int hi = min(N, lo + R);
  for (int e = bid * blockDim.x + threadIdx.x; e < E; e += nb * blockDim.x) {
    int d = __builtin_nontemporal_load(dst + e);
    int s = __builtin_nontemporal_load(src + e);
    float ww = __builtin_nontemporal_load(w + e);
    if (d >= lo && d < hi) {
      int pos = atomicAdd(&cur[d], 1);
      edge[pos] = make_int2(s, __float_as_int(ww));
      eidx[pos] = e;
    }
  }
}

// ---------------- canonicalize: selection-sort each node's segment by original edge index ----------------
__global__ __launch_bounds__(256) void sortpack_k(int* __restrict__ eidx, int2* __restrict__ edge,
                                                  const int* __restrict__ rp, int n) {
  int node = blockIdx.x * 256 + threadIdx.x;
  if (node >= n) return;
  int beg = rp[node], end = rp[node + 1];
  for (int i = beg; i < end - 1; ++i) {
    int mi = i, mv = eidx[i];
    for (int j = i + 1; j < end; ++j) {
      int v = eidx[j];
      if (v < mv) { mv = v; mi = j; }
    }
    if (mi != i) {
      eidx[mi] = eidx[i];
      eidx[i] = mv;
      int2 t = edge[i];
      edge[i] = edge[mi];
      edge[mi] = t;
    }
  }
}

// ---------------- x0 = relu(x @ W_in + b_in)  [MFMA hi/lo split, f32 out] ----------------
__global__ __launch_bounds__(256) void ingemm_k(const float* __restrict__ x, const float* __restrict__ Win,
                                                const float* __restrict__ bin, float* __restrict__ x0,
                                                int n) {
  int lane = threadIdx.x & 63;
  int wave = threadIdx.x >> 6;
  int col = lane & 15, grp = lane >> 4;
  f16x8 Bh[4][4], Bl[4][4];
#pragma unroll
  for (int c = 0; c < 4; ++c)
#pragma unroll
    for (int t = 0; t < 4; ++t) {
      f16x8 bh, bl;
#pragma unroll
      for (int j = 0; j < 8; ++j) {
        float wv = Win[(c * 32 + grp * 8 + j) * 64 + t * 16 + col];
        _Float16 hi = (_Float16)wv;
        bh[j] = hi;
        bl[j] = (_Float16)(wv - (float)hi);
      }
      Bh[c][t] = bh;
      Bl[c][t] = bl;
    }
  float bb[4];
#pragma unroll
  for (int t = 0; t < 4; ++t) bb[t] = bin[t * 16 + col];

  int node_base = (blockIdx.x * 4 + wave) * 16;
  if (node_base >= n) return;
  int arow = node_base + col;
  if (arow > n - 1) arow = n - 1;
  const float* xr = x + (size_t)arow * 128 + grp * 8;

  f32x4 acc[4];
  f32x4 z = {0.f, 0.f, 0.f, 0.f};
#pragma unroll
  for (int t = 0; t < 4; ++t) acc[t] = z;
#pragma unroll
  for (int c = 0; c < 4; ++c) {
    f32x4 lo = *(const f32x4*)(xr + c * 32);
    f32x4 hi = *(const f32x4*)(xr + c * 32 + 4);
    f16x8 ah, al;
#pragma unroll
    for (int j = 0; j < 4; ++j) {
      _Float16 h0 = (_Float16)lo[j];
      ah[j] = h0;
      al[j] = (_Float16)(lo[j] - (float)h0);
      _Float16 h1 = (_Float16)hi[j];
      ah[4 + j] = h1;
      al[4 + j] = (_Float16)(hi[j] - (float)h1);
    }
#pragma unroll
    for (int t = 0; t < 4; ++t) {
      acc[t] = __builtin_amdgcn_mfma_f32_16x16x32_f16(ah, Bh[c][t], acc[t], 0, 0, 0);
      acc[t] = __builtin_amdgcn_mfma_f32_16x16x32_f16(al, Bh[c][t], acc[t], 0, 0, 0);
      acc[t] = __builtin_amdgcn_mfma_f32_16x16x32_f16(ah, Bl[c][t], acc[t], 0, 0, 0);
    }
  }
#pragma unroll
  for (int t = 0; t < 4; ++t)
#pragma unroll
    for (int r = 0; r < 4; ++r) {
      int node = node_base + grp * 4 + r;
      if (node < n) {
        float o = acc[t][r] + bb[t];
        x0[(size_t)node * 64 + t * 16 + col] = fmaxf(o, 0.f);
      }
    }
}

// ---------------- fused layer: f32 SpMM gather -> f32 LDS -> hi/lo-A x hi/lo-B MFMA + f32 identity ----------------
__global__ __launch_bounds__(256) void layer_fused_k(const float4* __restrict__ hin4,
                                                     const float4* __restrict__ x04,
                                                     const int* __restrict__ rp, const int2* __restrict__ edge,
                                                     const float* __restrict__ W,
                                                     float* __restrict__ hout,
                                                     float beta, int n) {
  __shared__ float hh_lds[64][72];
  int lane = threadIdx.x & 63;
  int wave = threadIdx.x >> 6;
  int q = lane >> 4;   // node slot
  int sl = lane & 15;  // feature quad
  int blockStart = blockIdx.x * 64;

  // ---- gather phase (f32 h rows: one float4 per lane = 256B row per 16-lane group) ----
#pragma unroll
  for (int r = 0; r < 4; ++r) {
    int nib = wave * 16 + r * 4 + q;
    int node = blockStart + nib;
    float a0 = 0.f, a1 = 0.f, a2 = 0.f, a3 = 0.f;
    float4 xv = make_float4(0.f, 0.f, 0.f, 0.f);
    if (node < n) {
      int beg = rp[node];
      int end = rp[node + 1];
      xv = x04[(size_t)node * 16 + sl];
      for (int e = beg; e < end; e += 8) {
        int2 d[8];
#pragma unroll
        for (int j = 0; j < 8; ++j) d[j] = (e + j < end) ? edge[e + j] : make_int2(0, 0);
        float4 v[8];
#pragma unroll
        for (int j = 0; j < 8; ++j) v[j] = hin4[(size_t)d[j].x * 16 + sl];
#pragma unroll
        for (int j = 0; j < 8; ++j) {
          float w = __int_as_float(d[j].y);
          a0 = fmaf(v[j].x, w, a0);
          a1 = fmaf(v[j].y, w, a1);
          a2 = fmaf(v[j].z, w, a2);
          a3 = fmaf(v[j].w, w, a3);
        }
      }
    }
    float4 o;
    o.x = fmaf(0.9f, a0, 0.1f * xv.x);
    o.y = fmaf(0.9f, a1, 0.1f * xv.y);
    o.z = fmaf(0.9f, a2, 0.1f * xv.z);
    o.w = fmaf(0.9f, a3, 0.1f * xv.w);
    *(float4*)&hh_lds[nib][sl * 4] = o;
  }
  __syncthreads();

  // ---- GEMM phase: A = hi/lo(hh), B = hi/lo(W); 3-term product per chunk ----
  int col = lane & 15, grp = lane >> 4;
  f16x8 Bh[2][4], Bl[2][4];
#pragma unroll
  for (int c = 0; c < 2; ++c)
#pragma unroll
    for (int t = 0; t < 4; ++t) {
      f16x8 bh, bl;
#pragma unroll
      for (int j = 0; j < 8; ++j) {
        float wv = W[(c * 32 + grp * 8 + j) * 64 + t * 16 + col];
        _Float16 hi = (_Float16)wv;
        bh[j] = hi;
        bl[j] = (_Float16)(wv - (float)hi);
      }
      Bh[c][t] = bh;
      Bl[c][t] = bl;
    }
  f16x8 A0h, A0l, A1h, A1l;
#pragma unroll
  for (int j = 0; j < 8; ++j) {
    float v0 = hh_lds[wave * 16 + col][j + grp * 8];
    _Float16 h0 = (_Float16)v0;
    A0h[j] = h0;
    A0l[j] = (_Float16)(v0 - (float)h0);
    float v1 = hh_lds[wave * 16 + col][32 + j + grp * 8];
    _Float16 h1 = (_Float16)v1;
    A1h[j] = h1;
    A1l[j] = (_Float16)(v1 - (float)h1);
  }

  f32x4 acc[4];
  f32x4 z = {0.f, 0.f, 0.f, 0.f};
#pragma unroll
  for (int t = 0; t < 4; ++t) acc[t] = z;
#pragma unroll
  for (int t = 0; t < 4; ++t) {
    acc[t] = __builtin_amdgcn_mfma_f32_16x16x32_f16(A0h, Bh[0][t], acc[t], 0, 0, 0);
    acc[t] = __builtin_amdgcn_mfma_f32_16x16x32_f16(A1h, Bh[1][t], acc[t], 0, 0, 0);
    acc[t] = __builtin_amdgcn_mfma_f32_16x16x32_f16(A0l, Bh[0][t], acc[t], 0, 0, 0);
    acc[t] = __builtin_amdgcn_mfma_f32_16x16x32_f16(A1l, Bh[1][t], acc[t], 0, 0, 0);
    acc[t] = __builtin_amdgcn_mfma_f32_16x16x32_f16(A0h, Bl[0][t], acc[t], 0, 0, 0);
    acc[t] = __builtin_amdgcn_mfma_f32_16x16x32_f16(A1h, Bl[1][t], acc[t], 0, 0, 0);
  }
  float ob = 1.f - beta;
  int node_base = blockStart + wave * 16;
#pragma unroll
  for (int t = 0; t < 4; ++t)
#pragma unroll
    for (int r = 0; r < 4; ++r) {
      int node = node_base + grp * 4 + r;
      if (node < n) {
        float hv = hh_lds[wave * 16 + grp * 4 + r][t * 16 + col];  // exact f32 identity
        float o = ob * hv + beta * acc[t][r];
        hout[(size_t)node * 64 + t * 16 + col] = fmaxf(o, 0.f);
      }
    }
}

// ---------------- out = log_softmax(h @ W_out + b_out)  [MFMA hi/lo both operands, f32 in/out] ----------------
__global__ __launch_bounds__(256) void out_k(const float* __restrict__ h,
                                             const float* __restrict__ Wout, const float* __restrict__ bout,
                                             float* __restrict__ out, int n) {
  int lane = threadIdx.x & 63;
  int wave = threadIdx.x >> 6;
  int col = lane & 15, grp = lane >> 4;
  f16x8 Bh[2][3], Bl[2][3];
#pragma unroll
  for (int c = 0; c < 2; ++c)
#pragma unroll
    for (int t = 0; t < 3; ++t) {
      int cls = t * 16 + col;
      f16x8 bh, bl;
#pragma unroll
      for (int j = 0; j < 8; ++j) {
        float wv = (cls < 40) ? Wout[(c * 32 + grp * 8 + j) * 40 + cls] : 0.f;
        _Float16 hi = (_Float16)wv;
        bh[j] = hi;
        bl[j] = (_Float16)(wv - (float)hi);
      }
      Bh[c][t] = bh;
      Bl[c][t] = bl;
    }
  float bb[3];
#pragma unroll
  for (int t = 0; t < 3; ++t) {
    int cls = t * 16 + col;
    bb[t] = (cls < 40) ? bout[cls] : 0.f;
  }
  int node_base = (blockIdx.x * 4 + wave) * 16;
  if (node_base >= n) return;
  int arow = node_base + col;
  if (arow > n - 1) arow = n - 1;
  const float* rowp = h + (size_t)arow * 64 + grp * 8;
  f16x8 A0h, A0l, A1h, A1l;
#pragma unroll
  for (int j = 0; j < 8; ++j) {
    float v0 = rowp[j];
    _Float16 h0 = (_Float16)v0;
    A0h[j] = h0;
    A0l[j] = (_Float16)(v0 - (float)h0);
    float v1 = rowp[32 + j];
    _Float16 h1 = (_Float16)v1;
    A1h[j] = h1;
    A1l[j] = (_Float16)(v1 - (float)h1);
  }

  f32x4 acc[3];
  f32x4 z = {0.f, 0.f, 0.f, 0.f};
#pragma unroll
  for (int t = 0; t < 3; ++t) acc[t] = z;
#pragma unroll
  for (int t = 0; t < 3; ++t) {
    acc[t] = __builtin_amdgcn_mfma_f32_16x16x32_f16(A0h, Bh[0][t], acc[t], 0, 0, 0);
    acc[t] = __builtin_amdgcn_mfma_f32_16x16x32_f16(A1h, Bh[1][t], acc[t], 0, 0, 0);
    acc[t] = __builtin_amdgcn_mfma_f32_16x16x32_f16(A0l, Bh[0][t], acc[t], 0, 0, 0);
    acc[t] = __builtin_amdgcn_mfma_f32_16x16x32_f16(A1l, Bh[1][t], acc[t], 0, 0, 0);
    acc[t] = __builtin_amdgcn_mfma_f32_16x16x32_f16(A0h, Bl[0][t], acc[t], 0, 0, 0);
    acc[t] = __builtin_amdgcn_mfma_f32_16x16x32_f16(A1h, Bl[1][t], acc[t], 0, 0, 0);
  }
#pragma unroll
  for (int r = 0; r < 4; ++r) {
    int node = node_base + grp * 4 + r;
    float v0 = acc[0][r] + bb[0];
    float v1 = acc[1][r] + bb[1];
    float v2 = (32 + col < 40) ? (acc[2][r] + bb[2]) : -INFINITY;
    float m = fmaxf(fmaxf(v0, v1), v2);
#pragma unroll
    for (int mask = 1; mask <= 8; mask <<= 1) m = fmaxf(m, __shfl_xor(m, mask, 64));
    float p = expf(v0 - m) + expf(v1 - m) + ((32 + col < 40) ? expf(v2 - m) : 0.f);
#pragma unroll
    for (int mask = 1; mask <= 8; mask <<= 1) p += __shfl_xor(p, mask, 64);
    float ml = m + logf(p);
    if (node < n) {
      out[(size_t)node * 40 + col] = v0 - ml;
      out[(size_t)node * 40 + 16 + col] = v1 - ml;
      if (32 + col < 40) out[(size_t)node * 40 + 32 + col] = v2 - ml;
    }
  }
}

extern "C" void kernel_launch(void* const* d_in, const int* in_sizes, int n_in,
                              void* d_out, int out_size, void* d_ws, size_t ws_size,
                              hipStream_t stream) {
  const float* x = (const float*)d_in[0];
  const int* esrc = (const int*)d_in[1];
  const int* edst = (const int*)d_in[2];
  const float* ew = (const float*)d_in[3];
  const float* Win = (const float*)d_in[4];
  const float* bin = (const float*)d_in[5];
  const float* convW = (const float*)d_in[6];
  const float* Wout = (const float*)d_in[7];
  const float* bout = (const float*)d_in[8];
  float* out = (float*)d_out;

  const int N = in_sizes[0] / 128;
  const int E = in_sizes[1];
  const int NC = in_sizes[6] / (64 * 64);

  char* ws = (char*)d_ws;
  size_t off = 0;
  auto alloc = [&](size_t b) {
    void* p = ws + off;
    off += (b + 255) & ~(size_t)255;
    return p;
  };
  float* x0 = (float*)alloc((size_t)N * 64 * 4);
  float* ha = (float*)alloc((size_t)N * 64 * 4);
  float* hb = (float*)alloc((size_t)N * 64 * 4);
  int* deg = (int*)alloc((size_t)N * 4);
  int* rp = (int*)alloc((size_t)(N + 1) * 4);
  int* cur = (int*)alloc((size_t)N * 4);
  int* bsum = (int*)alloc(1024);
  int2* edge = (int2*)alloc((size_t)E * 8);
  int* eidx = (int*)alloc((size_t)E * 4);

  hipMemsetAsync(deg, 0, (size_t)N * 4, stream);
  hist_k<<<2048, 256, 0, stream>>>(edst, deg, E, N);
  int nb = (N + 1023) / 1024;
  scan1_k<<<nb, 1024, 0, stream>>>(deg, rp, bsum, N);
  scan2_k<<<1, 256, 0, stream>>>(bsum, nb);
  scan3_k<<<nb, 1024, 0, stream>>>(rp, cur, bsum, N, E);
  scatter_k<<<2048, 256, 0, stream>>>(esrc, edst, ew, cur, edge, eidx, E, N);
  sortpack_k<<<(N + 255) / 256, 256, 0, stream>>>(eidx, edge, rp, N);

  int gblocks = (N + 63) / 64;
  ingemm_k<<<gblocks, 256, 0, stream>>>(x, Win, bin, x0, N);

  const float* hin = x0;
  float* bufs[2] = {ha, hb};
  for (int l = 0; l < NC; ++l) {
    float beta = logf(0.5f / (float)(l + 1) + 1.0f);
    float* ho = bufs[l & 1];
    layer_fused_k<<<gblocks, 256, 0, stream>>>((const float4*)hin, (const float4*)x0, rp, edge,
                                               convW + (size_t)l * 64 * 64, ho, beta, N);
    hin = ho;
  }
  out_k<<<gblocks, 256, 0, stream>>>(hin, Wout, bout, out, N);
}

// Round 13
// 717.060 us; speedup vs baseline: 1.2045x; 1.0308x over previous
//
#include <hip/hip_runtime.h>
#include <math.h>

typedef _Float16 f16x8 __attribute__((ext_vector_type(8)));
typedef float f32x4 __attribute__((ext_vector_type(4)));

// ---------------- CSR build: 3-kernel exclusive scan ----------------
__global__ __launch_bounds__(1024) void scan1_k(const int* __restrict__ deg, int* __restrict__ rp,
                                                int* __restrict__ bsum, int n) {
  __shared__ int buf[2][1024];
  int tid = threadIdx.x;
  int i = blockIdx.x * 1024 + tid;
  int v = (i < n) ? deg[i] : 0;
  int pp = 0;
  buf[0][tid] = v;
  __syncthreads();
  for (int off = 1; off < 1024; off <<= 1) {
    int t = buf[pp][tid];
    if (tid >= off) t += buf[pp][tid - off];
    buf[pp ^ 1][tid] = t;
    pp ^= 1;
    __syncthreads();
  }
  int inc = buf[pp][tid];
  if (i < n) rp[i] = inc - v;
  if (tid == 1023) bsum[blockIdx.x] = inc;
}

__global__ __launch_bounds__(256) void scan2_k(int* __restrict__ bsum, int nb) {
  __shared__ int buf[2][256];
  int tid = threadIdx.x;
  int v = (tid < nb) ? bsum[tid] : 0;
  int pp = 0;
  buf[0][tid] = v;
  __syncthreads();
  for (int off = 1; off < 256; off <<= 1) {
    int t = buf[pp][tid];
    if (tid >= off) t += buf[pp][tid - off];
    buf[pp ^ 1][tid] = t;
    pp ^= 1;
    __syncthreads();
  }
  if (tid < nb) bsum[tid] = buf[pp][tid] - v;
}

__global__ __launch_bounds__(1024) void scan3_k(int* __restrict__ rp, int* __restrict__ cur,
                                                const int* __restrict__ bsum, int n, int E) {
  int i = blockIdx.x * 1024 + threadIdx.x;
  if (i < n) {
    int v = rp[i] + bsum[blockIdx.x];
    rp[i] = v;
    cur[i] = v;
  }
  if (i == 0) rp[n] = E;
}

// ---------------- CSR build: counting-sort scatter (XCD-partitioned, nt streams) ----------------
__global__ __launch_bounds__(256) void scatter_k(const int* __restrict__ src, const int* __restrict__ dst,
                                                 const float* __restrict__ w, int* __restrict__ cur,
                                                 int2* __restrict__ edge, int E, int N) {
  int xcd = blockIdx.x & 7;
  int bid = blockIdx.x >> 3;
  int nb = gridDim.x >> 3;
  int R = (N + 7) >> 3;
  int lo = xcd * R;
  int hi = min(N, lo + R);
  for (int e = bid * blockDim.x + threadIdx.x; e < E; e += nb * blockDim.x) {
    int d = __builtin_nontemporal_load(dst + e);
    int s = __builtin_nontemporal_load(src + e);
    float ww = __builtin_nontemporal_load(w + e);
    if (d >= lo && d < hi) {
      int pos = atomicAdd(&cur[d], 1);
      edge[pos] = make_int2(s, __float_as_int(ww));
    }
  }
}

// ---------------- canonicalize: selection-sort each node's segment by payload value ----------------
// Sorting the 8B payload itself (as u64) gives a canonical order independent of atomic
// arrival order -> bit-deterministic accumulation every call. Identical keys commute exactly.
__global__ __launch_bounds__(256) void sortpack_k(unsigned long long* __restrict__ edge,
                                                  const int* __restrict__ rp, int n) {
  int node = blockIdx.x * 256 + threadIdx.x;
  if (node >= n) return;
  int beg = rp[node], end = rp[node + 1];
  for (int i = beg; i < end - 1; ++i) {
    int mi = i;
    unsigned long long mv = edge[i];
    for (int j = i + 1; j < end; ++j) {
      unsigned long long v = edge[j];
      if (v < mv) { mv = v; mi = j; }
    }
    if (mi != i) {
      edge[mi] = edge[i];
      edge[i] = mv;
    }
  }
}

// ---------------- fused: histogram (XCD-partitioned) || x0 = relu(x @ W_in + b_in) ----------------
// Blocks [0, histBlocks) do the edge histogram; blocks [histBlocks, ...) do the input GEMM.
// The two are data-independent, so they overlap inside one launch.
__global__ __launch_bounds__(256) void histin_k(const int* __restrict__ dst, int* __restrict__ deg,
                                                int E, int N, int histBlocks,
                                                const float* __restrict__ x, const float* __restrict__ Win,
                                                const float* __restrict__ bin, float* __restrict__ x0) {
  if (blockIdx.x < histBlocks) {
    int xcd = blockIdx.x & 7;
    int bid = blockIdx.x >> 3;
    int nb = histBlocks >> 3;
    int R = (N + 7) >> 3;
    int lo = xcd * R;
    int hi = min(N, lo + R);
    for (int e = bid * blockDim.x + threadIdx.x; e < E; e += nb * blockDim.x) {
      int d = __builtin_nontemporal_load(dst + e);
      if (d >= lo && d < hi) atomicAdd(&deg[d], 1);
    }
    return;
  }
  // ---- ingemm part ----
  int lane = threadIdx.x & 63;
  int wave = threadIdx.x >> 6;
  int col = lane & 15, grp = lane >> 4;
  f16x8 Bh[4][4], Bl[4][4];
#pragma unroll
  for (int c = 0; c < 4; ++c)
#pragma unroll
    for (int t = 0; t < 4; ++t) {
      f16x8 bh, bl;
#pragma unroll
      for (int j = 0; j < 8; ++j) {
        float wv = Win[(c * 32 + grp * 8 + j) * 64 + t * 16 + col];
        _Float16 hi = (_Float16)wv;
        bh[j] = hi;
        bl[j] = (_Float16)(wv - (float)hi);
      }
      Bh[c][t] = bh;
      Bl[c][t] = bl;
    }
  float bb[4];
#pragma unroll
  for (int t = 0; t < 4; ++t) bb[t] = bin[t * 16 + col];

  int node_base = ((blockIdx.x - histBlocks) * 4 + wave) * 16;
  if (node_base >= N) return;
  int arow = node_base + col;
  if (arow > N - 1) arow = N - 1;
  const float* xr = x + (size_t)arow * 128 + grp * 8;

  f32x4 acc[4];
  f32x4 z = {0.f, 0.f, 0.f, 0.f};
#pragma unroll
  for (int t = 0; t < 4; ++t) acc[t] = z;
#pragma unroll
  for (int c = 0; c < 4; ++c) {
    f32x4 lo = *(const f32x4*)(xr + c * 32);
    f32x4 hi = *(const f32x4*)(xr + c * 32 + 4);
    f16x8 ah, al;
#pragma unroll
    for (int j = 0; j < 4; ++j) {
      _Float16 h0 = (_Float16)lo[j];
      ah[j] = h0;
      al[j] = (_Float16)(lo[j] - (float)h0);
      _Float16 h1 = (_Float16)hi[j];
      ah[4 + j] = h1;
      al[4 + j] = (_Float16)(hi[j] - (float)h1);
    }
#pragma unroll
    for (int t = 0; t < 4; ++t) {
      acc[t] = __builtin_amdgcn_mfma_f32_16x16x32_f16(ah, Bh[c][t], acc[t], 0, 0, 0);
      acc[t] = __builtin_amdgcn_mfma_f32_16x16x32_f16(al, Bh[c][t], acc[t], 0, 0, 0);
      acc[t] = __builtin_amdgcn_mfma_f32_16x16x32_f16(ah, Bl[c][t], acc[t], 0, 0, 0);
    }
  }
#pragma unroll
  for (int t = 0; t < 4; ++t)
#pragma unroll
    for (int r = 0; r < 4; ++r) {
      int node = node_base + grp * 4 + r;
      if (node < N) {
        float o = acc[t][r] + bb[t];
        x0[(size_t)node * 64 + t * 16 + col] = fmaxf(o, 0.f);
      }
    }
}

// ---------------- fused layer: f32 SpMM gather -> f32 LDS -> hi/lo-A x hi/lo-B MFMA + f32 identity ----------------
__global__ __launch_bounds__(256) void layer_fused_k(const float4* __restrict__ hin4,
                                                     const float4* __restrict__ x04,
                                                     const int* __restrict__ rp, const int2* __restrict__ edge,
                                                     const float* __restrict__ W,
                                                     float* __restrict__ hout,
                                                     float beta, int n) {
  __shared__ float hh_lds[64][72];
  int lane = threadIdx.x & 63;
  int wave = threadIdx.x >> 6;
  int q = lane >> 4;   // node slot
  int sl = lane & 15;  // feature quad
  int blockStart = blockIdx.x * 64;

  // ---- gather phase (f32 h rows: one float4 per lane = 256B row per 16-lane group) ----
#pragma unroll
  for (int r = 0; r < 4; ++r) {
    int nib = wave * 16 + r * 4 + q;
    int node = blockStart + nib;
    float a0 = 0.f, a1 = 0.f, a2 = 0.f, a3 = 0.f;
    float4 xv = make_float4(0.f, 0.f, 0.f, 0.f);
    if (node < n) {
      int beg = rp[node];
      int end = rp[node + 1];
      xv = x04[(size_t)node * 16 + sl];
      for (int e = beg; e < end; e += 8) {
        int2 d[8];
#pragma unroll
        for (int j = 0; j < 8; ++j) d[j] = (e + j < end) ? edge[e + j] : make_int2(0, 0);
        float4 v[8];
#pragma unroll
        for (int j = 0; j < 8; ++j) v[j] = hin4[(size_t)d[j].x * 16 + sl];
#pragma unroll
        for (int j = 0; j < 8; ++j) {
          float w = __int_as_float(d[j].y);
          a0 = fmaf(v[j].x, w, a0);
          a1 = fmaf(v[j].y, w, a1);
          a2 = fmaf(v[j].z, w, a2);
          a3 = fmaf(v[j].w, w, a3);
        }
      }
    }
    float4 o;
    o.x = fmaf(0.9f, a0, 0.1f * xv.x);
    o.y = fmaf(0.9f, a1, 0.1f * xv.y);
    o.z = fmaf(0.9f, a2, 0.1f * xv.z);
    o.w = fmaf(0.9f, a3, 0.1f * xv.w);
    *(float4*)&hh_lds[nib][sl * 4] = o;
  }
  __syncthreads();

  // ---- GEMM phase: A = hi/lo(hh), B = hi/lo(W); 3-term product per chunk ----
  int col = lane & 15, grp = lane >> 4;
  f16x8 Bh[2][4], Bl[2][4];
#pragma unroll
  for (int c = 0; c < 2; ++c)
#pragma unroll
    for (int t = 0; t < 4; ++t) {
      f16x8 bh, bl;
#pragma unroll
      for (int j = 0; j < 8; ++j) {
        float wv = W[(c * 32 + grp * 8 + j) * 64 + t * 16 + col];
        _Float16 hi = (_Float16)wv;
        bh[j] = hi;
        bl[j] = (_Float16)(wv - (float)hi);
      }
      Bh[c][t] = bh;
      Bl[c][t] = bl;
    }
  f16x8 A0h, A0l, A1h, A1l;
#pragma unroll
  for (int j = 0; j < 8; ++j) {
    float v0 = hh_lds[wave * 16 + col][j + grp * 8];
    _Float16 h0 = (_Float16)v0;
    A0h[j] = h0;
    A0l[j] = (_Float16)(v0 - (float)h0);
    float v1 = hh_lds[wave * 16 + col][32 + j + grp * 8];
    _Float16 h1 = (_Float16)v1;
    A1h[j] = h1;
    A1l[j] = (_Float16)(v1 - (float)h1);
  }

  f32x4 acc[4];
  f32x4 z = {0.f, 0.f, 0.f, 0.f};
#pragma unroll
  for (int t = 0; t < 4; ++t) acc[t] = z;
#pragma unroll
  for (int t = 0; t < 4; ++t) {
    acc[t] = __builtin_amdgcn_mfma_f32_16x16x32_f16(A0h, Bh[0][t], acc[t], 0, 0, 0);
    acc[t] = __builtin_amdgcn_mfma_f32_16x16x32_f16(A1h, Bh[1][t], acc[t], 0, 0, 0);
    acc[t] = __builtin_amdgcn_mfma_f32_16x16x32_f16(A0l, Bh[0][t], acc[t], 0, 0, 0);
    acc[t] = __builtin_amdgcn_mfma_f32_16x16x32_f16(A1l, Bh[1][t], acc[t], 0, 0, 0);
    acc[t] = __builtin_amdgcn_mfma_f32_16x16x32_f16(A0h, Bl[0][t], acc[t], 0, 0, 0);
    acc[t] = __builtin_amdgcn_mfma_f32_16x16x32_f16(A1h, Bl[1][t], acc[t], 0, 0, 0);
  }
  float ob = 1.f - beta;
  int node_base = blockStart + wave * 16;
#pragma unroll
  for (int t = 0; t < 4; ++t)
#pragma unroll
    for (int r = 0; r < 4; ++r) {
      int node = node_base + grp * 4 + r;
      if (node < n) {
        float hv = hh_lds[wave * 16 + grp * 4 + r][t * 16 + col];  // exact f32 identity
        float o = ob * hv + beta * acc[t][r];
        hout[(size_t)node * 64 + t * 16 + col] = fmaxf(o, 0.f);
      }
    }
}

// ---------------- out = log_softmax(h @ W_out + b_out)  [MFMA hi/lo both operands, f32 in/out] ----------------
__global__ __launch_bounds__(256) void out_k(const float* __restrict__ h,
                                             const float* __restrict__ Wout, const float* __restrict__ bout,
                                             float* __restrict__ out, int n) {
  int lane = threadIdx.x & 63;
  int wave = threadIdx.x >> 6;
  int col = lane & 15, grp = lane >> 4;
  f16x8 Bh[2][3], Bl[2][3];
#pragma unroll
  for (int c = 0; c < 2; ++c)
#pragma unroll
    for (int t = 0; t < 3; ++t) {
      int cls = t * 16 + col;
      f16x8 bh, bl;
#pragma unroll
      for (int j = 0; j < 8; ++j) {
        float wv = (cls < 40) ? Wout[(c * 32 + grp * 8 + j) * 40 + cls] : 0.f;
        _Float16 hi = (_Float16)wv;
        bh[j] = hi;
        bl[j] = (_Float16)(wv - (float)hi);
      }
      Bh[c][t] = bh;
      Bl[c][t] = bl;
    }
  float bb[3];
#pragma unroll
  for (int t = 0; t < 3; ++t) {
    int cls = t * 16 + col;
    bb[t] = (cls < 40) ? bout[cls] : 0.f;
  }
  int node_base = (blockIdx.x * 4 + wave) * 16;
  if (node_base >= n) return;
  int arow = node_base + col;
  if (arow > n - 1) arow = n - 1;
  const float* rowp = h + (size_t)arow * 64 + grp * 8;
  f16x8 A0h, A0l, A1h, A1l;
#pragma unroll
  for (int j = 0; j < 8; ++j) {
    float v0 = rowp[j];
    _Float16 h0 = (_Float16)v0;
    A0h[j] = h0;
    A0l[j] = (_Float16)(v0 - (float)h0);
    float v1 = rowp[32 + j];
    _Float16 h1 = (_Float16)v1;
    A1h[j] = h1;
    A1l[j] = (_Float16)(v1 - (float)h1);
  }

  f32x4 acc[3];
  f32x4 z = {0.f, 0.f, 0.f, 0.f};
#pragma unroll
  for (int t = 0; t < 3; ++t) acc[t] = z;
#pragma unroll
  for (int t = 0; t < 3; ++t) {
    acc[t] = __builtin_amdgcn_mfma_f32_16x16x32_f16(A0h, Bh[0][t], acc[t], 0, 0, 0);
    acc[t] = __builtin_amdgcn_mfma_f32_16x16x32_f16(A1h, Bh[1][t], acc[t], 0, 0, 0);
    acc[t] = __builtin_amdgcn_mfma_f32_16x16x32_f16(A0l, Bh[0][t], acc[t], 0, 0, 0);
    acc[t] = __builtin_amdgcn_mfma_f32_16x16x32_f16(A1l, Bh[1][t], acc[t], 0, 0, 0);
    acc[t] = __builtin_amdgcn_mfma_f32_16x16x32_f16(A0h, Bl[0][t], acc[t], 0, 0, 0);
    acc[t] = __builtin_amdgcn_mfma_f32_16x16x32_f16(A1h, Bl[1][t], acc[t], 0, 0, 0);
  }
#pragma unroll
  for (int r = 0; r < 4; ++r) {
    int node = node_base + grp * 4 + r;
    float v0 = acc[0][r] + bb[0];
    float v1 = acc[1][r] + bb[1];
    float v2 = (32 + col < 40) ? (acc[2][r] + bb[2]) : -INFINITY;
    float m = fmaxf(fmaxf(v0, v1), v2);
#pragma unroll
    for (int mask = 1; mask <= 8; mask <<= 1) m = fmaxf(m, __shfl_xor(m, mask, 64));
    float p = expf(v0 - m) + expf(v1 - m) + ((32 + col < 40) ? expf(v2 - m) : 0.f);
#pragma unroll
    for (int mask = 1; mask <= 8; mask <<= 1) p += __shfl_xor(p, mask, 64);
    float ml = m + logf(p);
    if (node < n) {
      out[(size_t)node * 40 + col] = v0 - ml;
      out[(size_t)node * 40 + 16 + col] = v1 - ml;
      if (32 + col < 40) out[(size_t)node * 40 + 32 + col] = v2 - ml;
    }
  }
}

extern "C" void kernel_launch(void* const* d_in, const int* in_sizes, int n_in,
                              void* d_out, int out_size, void* d_ws, size_t ws_size,
                              hipStream_t stream) {
  const float* x = (const float*)d_in[0];
  const int* esrc = (const int*)d_in[1];
  const int* edst = (const int*)d_in[2];
  const float* ew = (const float*)d_in[3];
  const float* Win = (const float*)d_in[4];
  const float* bin = (const float*)d_in[5];
  const float* convW = (const float*)d_in[6];
  const float* Wout = (const float*)d_in[7];
  const float* bout = (const float*)d_in[8];
  float* out = (float*)d_out;

  const int N = in_sizes[0] / 128;
  const int E = in_sizes[1];
  const int NC = in_sizes[6] / (64 * 64);

  char* ws = (char*)d_ws;
  size_t off = 0;
  auto alloc = [&](size_t b) {
    void* p = ws + off;
    off += (b + 255) & ~(size_t)255;
    return p;
  };
  float* x0 = (float*)alloc((size_t)N * 64 * 4);
  float* ha = (float*)alloc((size_t)N * 64 * 4);
  float* hb = (float*)alloc((size_t)N * 64 * 4);
  int* deg = (int*)alloc((size_t)N * 4);
  int* rp = (int*)alloc((size_t)(N + 1) * 4);
  int* cur = (int*)alloc((size_t)N * 4);
  int* bsum = (int*)alloc(1024);
  int2* edge = (int2*)alloc((size_t)E * 8);

  const int histBlocks = 2048;
  int gblocks = (N + 63) / 64;

  hipMemsetAsync(deg, 0, (size_t)N * 4, stream);
  // hist (blocks [0,2048)) || ingemm (blocks [2048, 2048+gblocks)) — independent work, one launch
  histin_k<<<histBlocks + gblocks, 256, 0, stream>>>(edst, deg, E, N, histBlocks, x, Win, bin, x0);
  int nb = (N + 1023) / 1024;
  scan1_k<<<nb, 1024, 0, stream>>>(deg, rp, bsum, N);
  scan2_k<<<1, 256, 0, stream>>>(bsum, nb);
  scan3_k<<<nb, 1024, 0, stream>>>(rp, cur, bsum, N, E);
  scatter_k<<<2048, 256, 0, stream>>>(esrc, edst, ew, cur, edge, E, N);
  sortpack_k<<<(N + 255) / 256, 256, 0, stream>>>((unsigned long long*)edge, rp, N);

  const float* hin = x0;
  float* bufs[2] = {ha, hb};
  for (int l = 0; l < NC; ++l) {
    float beta = logf(0.5f / (float)(l + 1) + 1.0f);
    float* ho = bufs[l & 1];
    layer_fused_k<<<gblocks, 256, 0, stream>>>((const float4*)hin, (const float4*)x0, rp, edge,
                                               convW + (size_t)l * 64 * 64, ho, beta, N);
    hin = ho;
  }
  out_k<<<gblocks, 256, 0, stream>>>(hin, Wout, bout, out, N);
}